// Round 6
// baseline (170.395 us; speedup 1.0000x reference)
//
#include <hip/hip_runtime.h>

// B=4, C=128, H=4, D=32, N=2048.  All-fp16 MFMA pipeline, canonical packed
// fragment format: value block (16ch tile ct, col n, quad q) lives at
// pk[(ct*2048+n)*16 + q*4 + j].  C-layout MFMA output == next B-frag (K=16);
// quad-pairs give K=32 b128 frags.  R5: 3 kernels (prep folded into qkv),
// attn reuses K/V frags across 2 Q-tiles/wave + 4-way key split.
typedef __attribute__((ext_vector_type(4))) float v4f;
typedef __attribute__((ext_vector_type(8))) _Float16 half8;
typedef __attribute__((ext_vector_type(4))) _Float16 half4;
typedef __attribute__((ext_vector_type(2))) _Float16 half2t;

constexpr float C2 = 0.17677669529663687f * 1.44269504088896341f;  // rsqrt(32)*log2e

__device__ __forceinline__ half4 pk4(float a, float b, float c, float d) {
  half2t lo = __builtin_bit_cast(half2t, __builtin_amdgcn_cvt_pkrtz(a, b));
  half2t hi = __builtin_bit_cast(half2t, __builtin_amdgcn_cvt_pkrtz(c, d));
  return __builtin_shufflevector(lo, hi, 0, 1, 2, 3);
}
__device__ __forceinline__ half8 pk8f4(const float4 a, const float4 b) {
  const half4 lo = pk4(a.x, a.y, a.z, a.w);
  const half4 hi = pk4(b.x, b.y, b.z, b.w);
  return __builtin_shufflevector(lo, hi, 0, 1, 2, 3, 4, 5, 6, 7);
}

// ---------------------------------------------------------------------------
// qkv: 8 waves per 16-col group; wave w owns 3 of 24 output tiles
// (Q0..7,K8..15,V16..23).  x gathered scalar from fp32 global (L1-hot across
// waves), w(q/k/v) fp32->fp16 inline.  Piggyback: wm/wc1/wc2 -> wts fp16
// (b==0, bx<72) and maskf (b==1, bx<4).  grid (128,4) x 512.
// ---------------------------------------------------------------------------
__global__ __launch_bounds__(512) void qkv(
    const float* __restrict__ x1, const float* __restrict__ x2,
    const float* __restrict__ wq, const float* __restrict__ bq,
    const float* __restrict__ wk, const float* __restrict__ bk,
    const float* __restrict__ wv, const float* __restrict__ bv,
    const float* __restrict__ wm, const float* __restrict__ wc1,
    const float* __restrict__ wc2, const unsigned char* __restrict__ mask,
    _Float16* __restrict__ Qpk, _Float16* __restrict__ Kpk,
    _Float16* __restrict__ Vpk, _Float16* __restrict__ wts,
    float* __restrict__ maskf) {
  const int b = blockIdx.y;
  const int bx = blockIdx.x;  // 16-col group == keytile for V
  const int tid = threadIdx.x, w = tid >> 6, lane = tid & 63;
  const int l = lane & 15, q = lane >> 4;
  const int n = bx * 16 + l;

  // piggyback work (block-uniform branches)
  if (b == 0 && bx < 72) {  // wm|wc1|wc2 -> fp16 wts: 72*512*4 = 147456 elems
    const int e = (bx * 512 + tid) * 4;
    const float* src;
    int base;
    if (e < 16384) { src = wm; base = 0; }
    else if (e < 81920) { src = wc1; base = 16384; }
    else { src = wc2; base = 81920; }
    const float4 t = *(const float4*)(src + (e - base));
    *(half4*)(wts + e) = pk4(t.x, t.y, t.z, t.w);
  } else if (b == 1 && bx < 4) {  // maskf: 4*512*4 = 8192
    const int e = (bx * 512 + tid) * 4;
    const unsigned mv = *(const unsigned*)(mask + e);
    float4 o;
    o.x = (mv & 0x000000ffu) ? 0.f : -1.0e6f * C2;
    o.y = (mv & 0x0000ff00u) ? 0.f : -1.0e6f * C2;
    o.z = (mv & 0x00ff0000u) ? 0.f : -1.0e6f * C2;
    o.w = (mv & 0xff000000u) ? 0.f : -1.0e6f * C2;
    *(float4*)(maskf + e) = o;
  }

  // x fragments: lane (l,q) holds ch kt*32+q*8..+7 at col n
  half8 x1f[4], x2f[4];
#pragma unroll
  for (int kt = 0; kt < 4; ++kt) {
    float4 a, c;
    const size_t rb = (size_t)(b * 128 + kt * 32 + q * 8) * 2048 + n;
    a.x = x1[rb]; a.y = x1[rb + 2048]; a.z = x1[rb + 4096]; a.w = x1[rb + 6144];
    c.x = x1[rb + 8192]; c.y = x1[rb + 10240]; c.z = x1[rb + 12288]; c.w = x1[rb + 14336];
    x1f[kt] = pk8f4(a, c);
    a.x = x2[rb]; a.y = x2[rb + 2048]; a.z = x2[rb + 4096]; a.w = x2[rb + 6144];
    c.x = x2[rb + 8192]; c.y = x2[rb + 10240]; c.z = x2[rb + 12288]; c.w = x2[rb + 14336];
    x2f[kt] = pk8f4(a, c);
  }

#pragma unroll
  for (int i = 0; i < 3; ++i) {
    const int t = w * 3 + i;  // wave-uniform
    if (t < 8) {              // Q tile mt=t : out = C2*(wq@x1 + bq)
      const int mt = t;
      v4f acc = *(const v4f*)(bq + mt * 16 + q * 4);
#pragma unroll
      for (int kt = 0; kt < 4; ++kt) {
        const float4 wa = *(const float4*)(wq + (mt * 16 + l) * 128 + kt * 32 + q * 8);
        const float4 wb = *(const float4*)(wq + (mt * 16 + l) * 128 + kt * 32 + q * 8 + 4);
        acc = __builtin_amdgcn_mfma_f32_16x16x32_f16(pk8f4(wa, wb), x1f[kt], acc, 0, 0, 0);
      }
      *(half4*)(Qpk + ((size_t)(b * 8 + mt) * 2048 + n) * 16 + q * 4) =
          pk4(acc[0] * C2, acc[1] * C2, acc[2] * C2, acc[3] * C2);
    } else if (t < 16) {  // K tile
      const int mt = t - 8;
      v4f acc = *(const v4f*)(bk + mt * 16 + q * 4);
#pragma unroll
      for (int kt = 0; kt < 4; ++kt) {
        const float4 wa = *(const float4*)(wk + (mt * 16 + l) * 128 + kt * 32 + q * 8);
        const float4 wb = *(const float4*)(wk + (mt * 16 + l) * 128 + kt * 32 + q * 8 + 4);
        acc = __builtin_amdgcn_mfma_f32_16x16x32_f16(pk8f4(wa, wb), x2f[kt], acc, 0, 0, 0);
      }
      *(half4*)(Kpk + ((size_t)(b * 8 + mt) * 2048 + n) * 16 + q * 4) =
          pk4(acc[0], acc[1], acc[2], acc[3]);
    } else {  // V^T tile ot (rows = keys of this col-group)
      const int ot = t - 16;
      const float bvv = bv[ot * 16 + l];
      v4f acc = {bvv, bvv, bvv, bvv};
#pragma unroll
      for (int kt = 0; kt < 4; ++kt) {
        const float4 wa = *(const float4*)(wv + (ot * 16 + l) * 128 + kt * 32 + q * 8);
        const float4 wb = *(const float4*)(wv + (ot * 16 + l) * 128 + kt * 32 + q * 8 + 4);
        acc = __builtin_amdgcn_mfma_f32_16x16x32_f16(x2f[kt], pk8f4(wa, wb), acc, 0, 0, 0);
      }
      *(half4*)(Vpk + (((size_t)(b * 4 + (ot >> 1)) * 128 + bx) * 32 +
                       (ot & 1) * 16 + l) * 16 + q * 4) =
          pk4(acc[0], acc[1], acc[2], acc[3]);
    }
  }
}

// ---------------------------------------------------------------------------
// attn: 2 Q-tiles per wave (K/V frag reuse), 4-way key split.  QK 16x16x32
// (S^T, mask bias in C-init); exp2 in regs; P regs ARE PV B-frags (16x16x16,
// V as A).  No LDS, no loop shuffles.  grid (16,16,4) x 256.
// ---------------------------------------------------------------------------
__global__ __launch_bounds__(256) void attn(
    const _Float16* __restrict__ Qpk, const _Float16* __restrict__ Kpk,
    const _Float16* __restrict__ Vpk, const float* __restrict__ maskf,
    _Float16* __restrict__ Opk, float* __restrict__ lsump) {
  const int bh = blockIdx.y, b = bh >> 2, h = bh & 3;
  const int part = blockIdx.z;
  const int tid = threadIdx.x, w = tid >> 6, lane = tid & 63;
  const int l = lane & 15, q = lane >> 4;
  const int nb = blockIdx.x * 128 + w * 32;  // wave's 32 queries

  const size_t qrow = (size_t)(b * 8 + h * 2 + (q >> 1)) * 2048;
  const half8 qf0 = *(const half8*)(Qpk + (qrow + nb + l) * 16 + (q & 1) * 8);
  const half8 qf1 = *(const half8*)(Qpk + (qrow + nb + 16 + l) * 16 + (q & 1) * 8);
  const _Float16* __restrict__ Kb = Kpk + qrow * 16 + (q & 1) * 8;
  const _Float16* __restrict__ Vb =
      Vpk + ((size_t)(b * 4 + h) * 128) * 512 + (size_t)l * 16 + q * 4;
  const float* __restrict__ mf = maskf + b * 2048;

  v4f oacc[2][2] = {{{0.f, 0.f, 0.f, 0.f}, {0.f, 0.f, 0.f, 0.f}},
                    {{0.f, 0.f, 0.f, 0.f}, {0.f, 0.f, 0.f, 0.f}}};
  float ls0 = 0.f, ls1 = 0.f;

  const int mbeg = part * 512;
  for (int m0 = mbeg; m0 < mbeg + 512; m0 += 64) {
    half4 pB[2][4];
#pragma unroll
    for (int mt = 0; mt < 4; ++mt) {
      const half8 kf = *(const half8*)(Kb + (size_t)(m0 + mt * 16 + l) * 16);
      const v4f biasv = *(const v4f*)(mf + m0 + mt * 16 + q * 4);
      const v4f s0 = __builtin_amdgcn_mfma_f32_16x16x32_f16(kf, qf0, biasv, 0, 0, 0);
      const v4f s1 = __builtin_amdgcn_mfma_f32_16x16x32_f16(kf, qf1, biasv, 0, 0, 0);
      const float a0 = exp2f(s0[0]), a1 = exp2f(s0[1]), a2 = exp2f(s0[2]),
                  a3 = exp2f(s0[3]);
      const float c0 = exp2f(s1[0]), c1 = exp2f(s1[1]), c2 = exp2f(s1[2]),
                  c3 = exp2f(s1[3]);
      ls0 += (a0 + a1) + (a2 + a3);
      ls1 += (c0 + c1) + (c2 + c3);
      pB[0][mt] = pk4(a0, a1, a2, a3);
      pB[1][mt] = pk4(c0, c1, c2, c3);
    }
#pragma unroll
    for (int mt = 0; mt < 4; ++mt) {
      const size_t vbase = (size_t)((m0 >> 4) + mt) * 512;
      const half4 vf0 = *(const half4*)(Vb + vbase);
      const half4 vf1 = *(const half4*)(Vb + vbase + 256);
      oacc[0][0] = __builtin_amdgcn_mfma_f32_16x16x16f16(vf0, pB[0][mt], oacc[0][0], 0, 0, 0);
      oacc[0][1] = __builtin_amdgcn_mfma_f32_16x16x16f16(vf1, pB[0][mt], oacc[0][1], 0, 0, 0);
      oacc[1][0] = __builtin_amdgcn_mfma_f32_16x16x16f16(vf0, pB[1][mt], oacc[1][0], 0, 0, 0);
      oacc[1][1] = __builtin_amdgcn_mfma_f32_16x16x16f16(vf1, pB[1][mt], oacc[1][1], 0, 0, 0);
    }
  }
  ls0 += __shfl_xor(ls0, 16);
  ls0 += __shfl_xor(ls0, 32);
  ls1 += __shfl_xor(ls1, 16);
  ls1 += __shfl_xor(ls1, 32);
  if (q == 0) {
    lsump[part * 32768 + bh * 2048 + nb + l] = ls0;
    lsump[part * 32768 + bh * 2048 + nb + 16 + l] = ls1;
  }
#pragma unroll
  for (int qt = 0; qt < 2; ++qt)
#pragma unroll
    for (int df = 0; df < 2; ++df)
      *(half4*)(Opk + (size_t)part * 1048576 +
                ((size_t)(b * 8 + h * 2 + df) * 2048 + nb + qt * 16 + l) * 16 +
                q * 4) = pk4(oacc[qt][df][0], oacc[qt][df][1], oacc[qt][df][2],
                             oacc[qt][df][3]);
}

// ---------------------------------------------------------------------------
// post: 8 waves per 16-col group; tile-split phases with LDS frag exchange.
// A: wave w -> cat tile 8+w.  B: wave w -> h1 tiles 2w,2w+1 (BN inline).
// C: wave w -> out tile w.  4-part O merge.  grid (128,4) x 512.
// ---------------------------------------------------------------------------
__global__ __launch_bounds__(512) void post(
    const float* __restrict__ x1, const _Float16* __restrict__ Opk,
    const float* __restrict__ lsump, const _Float16* __restrict__ wts,
    const float* __restrict__ bm, const float* __restrict__ bc1,
    const float* __restrict__ gamma, const float* __restrict__ beta,
    const float* __restrict__ mean, const float* __restrict__ var,
    const float* __restrict__ bc2, float* __restrict__ out) {
  const int b = blockIdx.y;
  const int n0 = blockIdx.x * 16;
  const int tid = threadIdx.x, w = tid >> 6, lane = tid & 63;
  const int l = lane & 15, q = lane >> 4;
  const int n = n0 + l;
  const _Float16* wm_h = wts;
  const _Float16* wc1_h = wts + 16384;
  const _Float16* wc2_h = wts + 81920;

  __shared__ _Float16 exA[8 * 256];   // phase-A outputs (cat tiles 8..15)
  __shared__ _Float16 exB[16 * 256];  // phase-B outputs (h1 tiles 0..15)

  float rlh[4];
#pragma unroll
  for (int hh = 0; hh < 4; ++hh) {
    const size_t idx = (size_t)(b * 4 + hh) * 2048 + n;
    rlh[hh] = 1.0f / (lsump[idx] + lsump[32768 + idx] + lsump[65536 + idx] +
                      lsump[98304 + idx]);
  }
  half4 of[8];
#pragma unroll
  for (int kt = 0; kt < 8; ++kt) {
    const size_t oa = ((size_t)(b * 8 + kt) * 2048 + n) * 16 + q * 4;
    const half4 a = *(const half4*)(Opk + oa);
    const half4 c = *(const half4*)(Opk + 1048576 + oa);
    const half4 d = *(const half4*)(Opk + 2097152 + oa);
    const half4 e = *(const half4*)(Opk + 3145728 + oa);
    const _Float16 rh = (_Float16)rlh[kt >> 1];
    const half4 rl4 = {rh, rh, rh, rh};
    of[kt] = ((a + c) + (d + e)) * rl4;
  }
  half4 catf[16];
  float xr[4];
#pragma unroll
  for (int kt = 0; kt < 8; ++kt) {
    const float v0 = x1[(size_t)(b * 128 + kt * 16 + q * 4 + 0) * 2048 + n];
    const float v1 = x1[(size_t)(b * 128 + kt * 16 + q * 4 + 1) * 2048 + n];
    const float v2 = x1[(size_t)(b * 128 + kt * 16 + q * 4 + 2) * 2048 + n];
    const float v3 = x1[(size_t)(b * 128 + kt * 16 + q * 4 + 3) * 2048 + n];
    if (kt == w) { xr[0] = v0; xr[1] = v1; xr[2] = v2; xr[3] = v3; }
    catf[kt] = pk4(v0, v1, v2, v3);
  }
  {  // phase A
    v4f acc = *(const v4f*)(bm + w * 16 + q * 4);
#pragma unroll
    for (int kt = 0; kt < 8; ++kt) {
      const half4 wf = *(const half4*)(wm_h + (w * 16 + l) * 128 + kt * 16 + q * 4);
      acc = __builtin_amdgcn_mfma_f32_16x16x16f16(wf, of[kt], acc, 0, 0, 0);
    }
    *(half4*)&exA[w * 256 + l * 16 + q * 4] = pk4(acc[0], acc[1], acc[2], acc[3]);
  }
  __syncthreads();
#pragma unroll
  for (int f = 0; f < 8; ++f)
    catf[8 + f] = *(const half4*)&exA[f * 256 + l * 16 + q * 4];
  // phase B
#pragma unroll
  for (int i = 0; i < 2; ++i) {
    const int mt = w * 2 + i;
    v4f acc = *(const v4f*)(bc1 + mt * 16 + q * 4);
#pragma unroll
    for (int kt = 0; kt < 16; ++kt) {
      const half4 wf = *(const half4*)(wc1_h + (mt * 16 + l) * 256 + kt * 16 + q * 4);
      acc = __builtin_amdgcn_mfma_f32_16x16x16f16(wf, catf[kt], acc, 0, 0, 0);
    }
    const v4f g = *(const v4f*)(gamma + mt * 16 + q * 4);
    const v4f bt = *(const v4f*)(beta + mt * 16 + q * 4);
    const v4f mn = *(const v4f*)(mean + mt * 16 + q * 4);
    const v4f vr = *(const v4f*)(var + mt * 16 + q * 4);
    float hh[4];
#pragma unroll
    for (int r = 0; r < 4; ++r) {
      const float a1 = g[r] * rsqrtf(vr[r] + 1e-5f);
      const float b1 = bt[r] - mn[r] * a1;
      hh[r] = fmaxf(acc[r] * a1 + b1, 0.f);
    }
    *(half4*)&exB[mt * 256 + l * 16 + q * 4] = pk4(hh[0], hh[1], hh[2], hh[3]);
  }
  __syncthreads();
  {  // phase C
    v4f acc = *(const v4f*)(bc2 + w * 16 + q * 4);
#pragma unroll
    for (int kt = 0; kt < 16; ++kt) {
      const half4 hfv = *(const half4*)&exB[kt * 256 + l * 16 + q * 4];
      const half4 wf = *(const half4*)(wc2_h + (w * 16 + l) * 256 + kt * 16 + q * 4);
      acc = __builtin_amdgcn_mfma_f32_16x16x16f16(wf, hfv, acc, 0, 0, 0);
    }
#pragma unroll
    for (int r = 0; r < 4; ++r)
      out[(size_t)(b * 128 + w * 16 + q * 4 + r) * 2048 + n] = acc[r] + xr[r];
  }
}

// ---------------------------------------------------------------------------
extern "C" void kernel_launch(void* const* d_in, const int* in_sizes, int n_in,
                              void* d_out, int out_size, void* d_ws,
                              size_t ws_size, hipStream_t stream) {
  const float* x1 = (const float*)d_in[0];
  const float* x2 = (const float*)d_in[1];
  const unsigned char* kv_mask = (const unsigned char*)d_in[2];
  const float* wq = (const float*)d_in[3];
  const float* bq = (const float*)d_in[4];
  const float* wk = (const float*)d_in[5];
  const float* bk = (const float*)d_in[6];
  const float* wv = (const float*)d_in[7];
  const float* bv = (const float*)d_in[8];
  const float* wm = (const float*)d_in[9];
  const float* bm = (const float*)d_in[10];
  const float* wc1 = (const float*)d_in[11];
  const float* bc1 = (const float*)d_in[12];
  const float* bn_gamma = (const float*)d_in[13];
  const float* bn_beta = (const float*)d_in[14];
  const float* bn_mean = (const float*)d_in[15];
  const float* bn_var = (const float*)d_in[16];
  const float* wc2 = (const float*)d_in[17];
  const float* bc2 = (const float*)d_in[18];
  float* out = (float*)d_out;

  // ws: Qpk 2M | Kpk 2M | Vpk 2M | Opk 8M (4 parts) | wts 288K | lsump 512K |
  //     maskf 32K
  char* p = (char*)d_ws;
  _Float16* Qpk = (_Float16*)p;
  _Float16* Kpk = (_Float16*)(p + (size_t)2 * 1024 * 1024);
  _Float16* Vpk = (_Float16*)(p + (size_t)4 * 1024 * 1024);
  _Float16* Opk = (_Float16*)(p + (size_t)6 * 1024 * 1024);
  _Float16* wts = (_Float16*)(p + (size_t)14 * 1024 * 1024);
  float* lsump = (float*)(p + (size_t)14 * 1024 * 1024 + 512 * 1024);
  float* maskf = lsump + 4 * 32768;

  qkv<<<dim3(128, 4), 512, 0, stream>>>(x1, x2, wq, bq, wk, bk, wv, bv, wm,
                                        wc1, wc2, kv_mask, Qpk, Kpk, Vpk, wts,
                                        maskf);
  attn<<<dim3(16, 16, 4), 256, 0, stream>>>(Qpk, Kpk, Vpk, maskf, Opk, lsump);
  post<<<dim3(128, 4), 512, 0, stream>>>(x1, Opk, lsump, wts, bm, bc1,
                                         bn_gamma, bn_beta, bn_mean, bn_var,
                                         bc2, out);
}

// Round 7
// 168.019 us; speedup vs baseline: 1.0141x; 1.0141x over previous
//
#include <hip/hip_runtime.h>

// B=4, C=128, H=4, D=32, N=2048.  All-fp16 MFMA pipeline, canonical packed
// fragment format: value block (16ch tile ct, col n, quad q) lives at
// pk[(ct*2048+n)*16 + q*4 + j].  C-layout MFMA output == next B-frag (K=16);
// quad-pairs give K=32 b128 frags.  R6: LDS-staged K/V in attn (4-wave reuse,
// 1-barrier double buffer) and LDS-staged x in qkv.
typedef __attribute__((ext_vector_type(4))) float v4f;
typedef __attribute__((ext_vector_type(8))) _Float16 half8;
typedef __attribute__((ext_vector_type(4))) _Float16 half4;
typedef __attribute__((ext_vector_type(2))) _Float16 half2t;

constexpr float C2 = 0.17677669529663687f * 1.44269504088896341f;  // rsqrt(32)*log2e

__device__ __forceinline__ half4 pk4(float a, float b, float c, float d) {
  half2t lo = __builtin_bit_cast(half2t, __builtin_amdgcn_cvt_pkrtz(a, b));
  half2t hi = __builtin_bit_cast(half2t, __builtin_amdgcn_cvt_pkrtz(c, d));
  return __builtin_shufflevector(lo, hi, 0, 1, 2, 3);
}
__device__ __forceinline__ half8 pk8f4(const float4 a, const float4 b) {
  const half4 lo = pk4(a.x, a.y, a.z, a.w);
  const half4 hi = pk4(b.x, b.y, b.z, b.w);
  return __builtin_shufflevector(lo, hi, 0, 1, 2, 3, 4, 5, 6, 7);
}

// ---------------------------------------------------------------------------
// qkv: 8 waves per 16-col group; wave w owns 3 of 24 output tiles
// (Q0..7,K8..15,V16..23).  x1/x2 tile staged through LDS as fp16 [n][ch]
// (stride 136: b128 frags, 2-way banks = free).  Piggyback: wm/wc1/wc2 -> wts
// fp16 (b==0) and maskf (b==1).  grid (128,4) x 512.
// ---------------------------------------------------------------------------
__global__ __launch_bounds__(512) void qkv(
    const float* __restrict__ x1, const float* __restrict__ x2,
    const float* __restrict__ wq, const float* __restrict__ bq,
    const float* __restrict__ wk, const float* __restrict__ bk,
    const float* __restrict__ wv, const float* __restrict__ bv,
    const float* __restrict__ wm, const float* __restrict__ wc1,
    const float* __restrict__ wc2, const unsigned char* __restrict__ mask,
    _Float16* __restrict__ Qpk, _Float16* __restrict__ Kpk,
    _Float16* __restrict__ Vpk, _Float16* __restrict__ wts,
    float* __restrict__ maskf) {
  const int b = blockIdx.y;
  const int bx = blockIdx.x;  // 16-col group == keytile for V
  const int tid = threadIdx.x, w = tid >> 6, lane = tid & 63;
  const int l = lane & 15, q = lane >> 4;
  const int n0 = bx * 16;
  const int n = n0 + l;

  __shared__ _Float16 x1s[16 * 136];
  __shared__ _Float16 x2s[16 * 136];

  // piggyback work (block-uniform branches)
  if (b == 0 && bx < 72) {  // wm|wc1|wc2 -> fp16 wts: 72*512*4 = 147456 elems
    const int e = (bx * 512 + tid) * 4;
    const float* src;
    int base;
    if (e < 16384) { src = wm; base = 0; }
    else if (e < 81920) { src = wc1; base = 16384; }
    else { src = wc2; base = 81920; }
    const float4 t = *(const float4*)(src + (e - base));
    *(half4*)(wts + e) = pk4(t.x, t.y, t.z, t.w);
  } else if (b == 1 && bx < 4) {  // maskf: 4*512*4 = 8192
    const int e = (bx * 512 + tid) * 4;
    const unsigned mv = *(const unsigned*)(mask + e);
    float4 o;
    o.x = (mv & 0x000000ffu) ? 0.f : -1.0e6f * C2;
    o.y = (mv & 0x0000ff00u) ? 0.f : -1.0e6f * C2;
    o.z = (mv & 0x00ff0000u) ? 0.f : -1.0e6f * C2;
    o.w = (mv & 0xff000000u) ? 0.f : -1.0e6f * C2;
    *(float4*)(maskf + e) = o;
  }

  {  // stage x tiles: thread -> (ch, 4 cols), fp32->fp16, LDS [n][ch]
    const int ch = tid >> 2, seg = tid & 3;
    const float4 a = *(const float4*)(x1 + (size_t)(b * 128 + ch) * 2048 + n0 + seg * 4);
    const float4 c = *(const float4*)(x2 + (size_t)(b * 128 + ch) * 2048 + n0 + seg * 4);
    x1s[(seg * 4 + 0) * 136 + ch] = (_Float16)a.x;
    x1s[(seg * 4 + 1) * 136 + ch] = (_Float16)a.y;
    x1s[(seg * 4 + 2) * 136 + ch] = (_Float16)a.z;
    x1s[(seg * 4 + 3) * 136 + ch] = (_Float16)a.w;
    x2s[(seg * 4 + 0) * 136 + ch] = (_Float16)c.x;
    x2s[(seg * 4 + 1) * 136 + ch] = (_Float16)c.y;
    x2s[(seg * 4 + 2) * 136 + ch] = (_Float16)c.z;
    x2s[(seg * 4 + 3) * 136 + ch] = (_Float16)c.w;
  }
  __syncthreads();

  half8 x1f[4], x2f[4];
#pragma unroll
  for (int kt = 0; kt < 4; ++kt) {
    x1f[kt] = *(const half8*)&x1s[l * 136 + kt * 32 + q * 8];
    x2f[kt] = *(const half8*)&x2s[l * 136 + kt * 32 + q * 8];
  }

#pragma unroll
  for (int i = 0; i < 3; ++i) {
    const int t = w * 3 + i;  // wave-uniform
    if (t < 8) {              // Q tile mt=t : out = C2*(wq@x1 + bq)
      const int mt = t;
      v4f acc = *(const v4f*)(bq + mt * 16 + q * 4);
#pragma unroll
      for (int kt = 0; kt < 4; ++kt) {
        const float4 wa = *(const float4*)(wq + (mt * 16 + l) * 128 + kt * 32 + q * 8);
        const float4 wb = *(const float4*)(wq + (mt * 16 + l) * 128 + kt * 32 + q * 8 + 4);
        acc = __builtin_amdgcn_mfma_f32_16x16x32_f16(pk8f4(wa, wb), x1f[kt], acc, 0, 0, 0);
      }
      *(half4*)(Qpk + ((size_t)(b * 8 + mt) * 2048 + n) * 16 + q * 4) =
          pk4(acc[0] * C2, acc[1] * C2, acc[2] * C2, acc[3] * C2);
    } else if (t < 16) {  // K tile
      const int mt = t - 8;
      v4f acc = *(const v4f*)(bk + mt * 16 + q * 4);
#pragma unroll
      for (int kt = 0; kt < 4; ++kt) {
        const float4 wa = *(const float4*)(wk + (mt * 16 + l) * 128 + kt * 32 + q * 8);
        const float4 wb = *(const float4*)(wk + (mt * 16 + l) * 128 + kt * 32 + q * 8 + 4);
        acc = __builtin_amdgcn_mfma_f32_16x16x32_f16(pk8f4(wa, wb), x2f[kt], acc, 0, 0, 0);
      }
      *(half4*)(Kpk + ((size_t)(b * 8 + mt) * 2048 + n) * 16 + q * 4) =
          pk4(acc[0], acc[1], acc[2], acc[3]);
    } else {  // V^T tile ot (rows = keys of this col-group)
      const int ot = t - 16;
      const float bvv = bv[ot * 16 + l];
      v4f acc = {bvv, bvv, bvv, bvv};
#pragma unroll
      for (int kt = 0; kt < 4; ++kt) {
        const float4 wa = *(const float4*)(wv + (ot * 16 + l) * 128 + kt * 32 + q * 8);
        const float4 wb = *(const float4*)(wv + (ot * 16 + l) * 128 + kt * 32 + q * 8 + 4);
        acc = __builtin_amdgcn_mfma_f32_16x16x32_f16(x2f[kt], pk8f4(wa, wb), acc, 0, 0, 0);
      }
      *(half4*)(Vpk + (((size_t)(b * 4 + (ot >> 1)) * 128 + bx) * 32 +
                       (ot & 1) * 16 + l) * 16 + q * 4) =
          pk4(acc[0], acc[1], acc[2], acc[3]);
    }
  }
}

// ---------------------------------------------------------------------------
// attn: 2 Q-tiles per wave, 4-way key split.  K/V chunks (64 keys) staged in
// LDS, shared by the block's 4 waves, double-buffered with ONE barrier per
// chunk.  QK 16x16x32 (S^T, mask bias in C-init); exp2 in regs; P regs ARE
// PV B-frags (16x16x16, V as A).  grid (16,16,4) x 256.
// ---------------------------------------------------------------------------
__global__ __launch_bounds__(256) void attn(
    const _Float16* __restrict__ Qpk, const _Float16* __restrict__ Kpk,
    const _Float16* __restrict__ Vpk, const float* __restrict__ maskf,
    _Float16* __restrict__ Opk, float* __restrict__ lsump) {
  const int bh = blockIdx.y, b = bh >> 2, h = bh & 3;
  const int part = blockIdx.z;
  const int tid = threadIdx.x, w = tid >> 6, lane = tid & 63;
  const int l = lane & 15, q = lane >> 4;
  const int nb = blockIdx.x * 128 + w * 32;  // wave's 32 queries

  // K: [ct][k][16] rows padded to 24 halfs, ct stride 1544 (bank-skewed).
  // V: [tile][d][16] rows padded to 24 halfs, tile stride 768.
  __shared__ _Float16 ldsK[2][3088];
  __shared__ _Float16 ldsV[2][3072];

  const size_t qrow = (size_t)(b * 8 + h * 2 + (q >> 1)) * 2048;
  const half8 qf0 = *(const half8*)(Qpk + (qrow + nb + l) * 16 + (q & 1) * 8);
  const half8 qf1 = *(const half8*)(Qpk + (qrow + nb + 16 + l) * 16 + (q & 1) * 8);
  const _Float16* __restrict__ Kg = Kpk + (size_t)(b * 8 + h * 2) * 2048 * 16;
  const _Float16* __restrict__ Vg = Vpk + (size_t)((b * 4 + h) * 128) * 512;
  const float* __restrict__ mf = maskf + b * 2048;

  // staging indices (thread-static)
  const int kct = tid >> 7, kk = (tid >> 1) & 63, khf = tid & 1;
  const int vt = tid >> 6, vd = (tid >> 1) & 31;

  v4f oacc[2][2] = {{{0.f, 0.f, 0.f, 0.f}, {0.f, 0.f, 0.f, 0.f}},
                    {{0.f, 0.f, 0.f, 0.f}, {0.f, 0.f, 0.f, 0.f}}};
  float ls0 = 0.f, ls1 = 0.f;
  const int mbeg = part * 512;

  half8 kr = *(const half8*)(Kg + ((size_t)kct * 2048 + mbeg + kk) * 16 + khf * 8);
  half8 vr = *(const half8*)(Vg + (size_t)((mbeg >> 4) + vt) * 512 + vd * 16 + khf * 8);
  *(half8*)&ldsK[0][kct * 1544 + kk * 24 + khf * 8] = kr;
  *(half8*)&ldsV[0][vt * 768 + vd * 24 + khf * 8] = vr;
  __syncthreads();

  for (int i = 0; i < 8; ++i) {
    const int m0 = mbeg + i * 64;
    const int cur = i & 1;
    if (i < 7) {  // prefetch next chunk to regs
      kr = *(const half8*)(Kg + ((size_t)kct * 2048 + m0 + 64 + kk) * 16 + khf * 8);
      vr = *(const half8*)(Vg + (size_t)(((m0 + 64) >> 4) + vt) * 512 + vd * 16 + khf * 8);
    }
    half4 pB[2][4];
#pragma unroll
    for (int mt = 0; mt < 4; ++mt) {
      const half8 kf =
          *(const half8*)&ldsK[cur][(q >> 1) * 1544 + (mt * 16 + l) * 24 + (q & 1) * 8];
      const v4f biasv = *(const v4f*)(mf + m0 + mt * 16 + q * 4);
      const v4f s0 = __builtin_amdgcn_mfma_f32_16x16x32_f16(kf, qf0, biasv, 0, 0, 0);
      const v4f s1 = __builtin_amdgcn_mfma_f32_16x16x32_f16(kf, qf1, biasv, 0, 0, 0);
      const float a0 = exp2f(s0[0]), a1 = exp2f(s0[1]), a2 = exp2f(s0[2]),
                  a3 = exp2f(s0[3]);
      const float c0 = exp2f(s1[0]), c1 = exp2f(s1[1]), c2 = exp2f(s1[2]),
                  c3 = exp2f(s1[3]);
      ls0 += (a0 + a1) + (a2 + a3);
      ls1 += (c0 + c1) + (c2 + c3);
      pB[0][mt] = pk4(a0, a1, a2, a3);
      pB[1][mt] = pk4(c0, c1, c2, c3);
    }
#pragma unroll
    for (int mt = 0; mt < 4; ++mt) {
      const half4 vf0 = *(const half4*)&ldsV[cur][mt * 768 + l * 24 + q * 4];
      const half4 vf1 = *(const half4*)&ldsV[cur][mt * 768 + (16 + l) * 24 + q * 4];
      oacc[0][0] = __builtin_amdgcn_mfma_f32_16x16x16f16(vf0, pB[0][mt], oacc[0][0], 0, 0, 0);
      oacc[0][1] = __builtin_amdgcn_mfma_f32_16x16x16f16(vf1, pB[0][mt], oacc[0][1], 0, 0, 0);
      oacc[1][0] = __builtin_amdgcn_mfma_f32_16x16x16f16(vf0, pB[1][mt], oacc[1][0], 0, 0, 0);
      oacc[1][1] = __builtin_amdgcn_mfma_f32_16x16x16f16(vf1, pB[1][mt], oacc[1][1], 0, 0, 0);
    }
    if (i < 7) {
      *(half8*)&ldsK[cur ^ 1][kct * 1544 + kk * 24 + khf * 8] = kr;
      *(half8*)&ldsV[cur ^ 1][vt * 768 + vd * 24 + khf * 8] = vr;
      __syncthreads();
    }
  }
  ls0 += __shfl_xor(ls0, 16);
  ls0 += __shfl_xor(ls0, 32);
  ls1 += __shfl_xor(ls1, 16);
  ls1 += __shfl_xor(ls1, 32);
  if (q == 0) {
    lsump[part * 32768 + bh * 2048 + nb + l] = ls0;
    lsump[part * 32768 + bh * 2048 + nb + 16 + l] = ls1;
  }
#pragma unroll
  for (int qt = 0; qt < 2; ++qt)
#pragma unroll
    for (int df = 0; df < 2; ++df)
      *(half4*)(Opk + (size_t)part * 1048576 +
                ((size_t)(b * 8 + h * 2 + df) * 2048 + nb + qt * 16 + l) * 16 +
                q * 4) = pk4(oacc[qt][df][0], oacc[qt][df][1], oacc[qt][df][2],
                             oacc[qt][df][3]);
}

// ---------------------------------------------------------------------------
// post: 8 waves per 16-col group; tile-split phases with LDS frag exchange.
// A: wave w -> cat tile 8+w.  B: wave w -> h1 tiles 2w,2w+1 (BN inline).
// C: wave w -> out tile w.  4-part O merge.  grid (128,4) x 512.
// ---------------------------------------------------------------------------
__global__ __launch_bounds__(512) void post(
    const float* __restrict__ x1, const _Float16* __restrict__ Opk,
    const float* __restrict__ lsump, const _Float16* __restrict__ wts,
    const float* __restrict__ bm, const float* __restrict__ bc1,
    const float* __restrict__ gamma, const float* __restrict__ beta,
    const float* __restrict__ mean, const float* __restrict__ var,
    const float* __restrict__ bc2, float* __restrict__ out) {
  const int b = blockIdx.y;
  const int n0 = blockIdx.x * 16;
  const int tid = threadIdx.x, w = tid >> 6, lane = tid & 63;
  const int l = lane & 15, q = lane >> 4;
  const int n = n0 + l;
  const _Float16* wm_h = wts;
  const _Float16* wc1_h = wts + 16384;
  const _Float16* wc2_h = wts + 81920;

  __shared__ _Float16 exA[8 * 256];   // phase-A outputs (cat tiles 8..15)
  __shared__ _Float16 exB[16 * 256];  // phase-B outputs (h1 tiles 0..15)

  float rlh[4];
#pragma unroll
  for (int hh = 0; hh < 4; ++hh) {
    const size_t idx = (size_t)(b * 4 + hh) * 2048 + n;
    rlh[hh] = 1.0f / (lsump[idx] + lsump[32768 + idx] + lsump[65536 + idx] +
                      lsump[98304 + idx]);
  }
  half4 of[8];
#pragma unroll
  for (int kt = 0; kt < 8; ++kt) {
    const size_t oa = ((size_t)(b * 8 + kt) * 2048 + n) * 16 + q * 4;
    const half4 a = *(const half4*)(Opk + oa);
    const half4 c = *(const half4*)(Opk + 1048576 + oa);
    const half4 d = *(const half4*)(Opk + 2097152 + oa);
    const half4 e = *(const half4*)(Opk + 3145728 + oa);
    const _Float16 rh = (_Float16)rlh[kt >> 1];
    const half4 rl4 = {rh, rh, rh, rh};
    of[kt] = ((a + c) + (d + e)) * rl4;
  }
  half4 catf[16];
  float xr[4];
#pragma unroll
  for (int kt = 0; kt < 8; ++kt) {
    const float v0 = x1[(size_t)(b * 128 + kt * 16 + q * 4 + 0) * 2048 + n];
    const float v1 = x1[(size_t)(b * 128 + kt * 16 + q * 4 + 1) * 2048 + n];
    const float v2 = x1[(size_t)(b * 128 + kt * 16 + q * 4 + 2) * 2048 + n];
    const float v3 = x1[(size_t)(b * 128 + kt * 16 + q * 4 + 3) * 2048 + n];
    if (kt == w) { xr[0] = v0; xr[1] = v1; xr[2] = v2; xr[3] = v3; }
    catf[kt] = pk4(v0, v1, v2, v3);
  }
  {  // phase A
    v4f acc = *(const v4f*)(bm + w * 16 + q * 4);
#pragma unroll
    for (int kt = 0; kt < 8; ++kt) {
      const half4 wf = *(const half4*)(wm_h + (w * 16 + l) * 128 + kt * 16 + q * 4);
      acc = __builtin_amdgcn_mfma_f32_16x16x16f16(wf, of[kt], acc, 0, 0, 0);
    }
    *(half4*)&exA[w * 256 + l * 16 + q * 4] = pk4(acc[0], acc[1], acc[2], acc[3]);
  }
  __syncthreads();
#pragma unroll
  for (int f = 0; f < 8; ++f)
    catf[8 + f] = *(const half4*)&exA[f * 256 + l * 16 + q * 4];
  // phase B
#pragma unroll
  for (int i = 0; i < 2; ++i) {
    const int mt = w * 2 + i;
    v4f acc = *(const v4f*)(bc1 + mt * 16 + q * 4);
#pragma unroll
    for (int kt = 0; kt < 16; ++kt) {
      const half4 wf = *(const half4*)(wc1_h + (mt * 16 + l) * 256 + kt * 16 + q * 4);
      acc = __builtin_amdgcn_mfma_f32_16x16x16f16(wf, catf[kt], acc, 0, 0, 0);
    }
    const v4f g = *(const v4f*)(gamma + mt * 16 + q * 4);
    const v4f bt = *(const v4f*)(beta + mt * 16 + q * 4);
    const v4f mn = *(const v4f*)(mean + mt * 16 + q * 4);
    const v4f vr = *(const v4f*)(var + mt * 16 + q * 4);
    float hh[4];
#pragma unroll
    for (int r = 0; r < 4; ++r) {
      const float a1 = g[r] * rsqrtf(vr[r] + 1e-5f);
      const float b1 = bt[r] - mn[r] * a1;
      hh[r] = fmaxf(acc[r] * a1 + b1, 0.f);
    }
    *(half4*)&exB[mt * 256 + l * 16 + q * 4] = pk4(hh[0], hh[1], hh[2], hh[3]);
  }
  __syncthreads();
  {  // phase C
    v4f acc = *(const v4f*)(bc2 + w * 16 + q * 4);
#pragma unroll
    for (int kt = 0; kt < 16; ++kt) {
      const half4 hfv = *(const half4*)&exB[kt * 256 + l * 16 + q * 4];
      const half4 wf = *(const half4*)(wc2_h + (w * 16 + l) * 256 + kt * 16 + q * 4);
      acc = __builtin_amdgcn_mfma_f32_16x16x16f16(wf, hfv, acc, 0, 0, 0);
    }
#pragma unroll
    for (int r = 0; r < 4; ++r)
      out[(size_t)(b * 128 + w * 16 + q * 4 + r) * 2048 + n] = acc[r] + xr[r];
  }
}

// ---------------------------------------------------------------------------
extern "C" void kernel_launch(void* const* d_in, const int* in_sizes, int n_in,
                              void* d_out, int out_size, void* d_ws,
                              size_t ws_size, hipStream_t stream) {
  const float* x1 = (const float*)d_in[0];
  const float* x2 = (const float*)d_in[1];
  const unsigned char* kv_mask = (const unsigned char*)d_in[2];
  const float* wq = (const float*)d_in[3];
  const float* bq = (const float*)d_in[4];
  const float* wk = (const float*)d_in[5];
  const float* bk = (const float*)d_in[6];
  const float* wv = (const float*)d_in[7];
  const float* bv = (const float*)d_in[8];
  const float* wm = (const float*)d_in[9];
  const float* bm = (const float*)d_in[10];
  const float* wc1 = (const float*)d_in[11];
  const float* bc1 = (const float*)d_in[12];
  const float* bn_gamma = (const float*)d_in[13];
  const float* bn_beta = (const float*)d_in[14];
  const float* bn_mean = (const float*)d_in[15];
  const float* bn_var = (const float*)d_in[16];
  const float* wc2 = (const float*)d_in[17];
  const float* bc2 = (const float*)d_in[18];
  float* out = (float*)d_out;

  // ws: Qpk 2M | Kpk 2M | Vpk 2M | Opk 8M (4 parts) | wts 288K | lsump 512K |
  //     maskf 32K
  char* p = (char*)d_ws;
  _Float16* Qpk = (_Float16*)p;
  _Float16* Kpk = (_Float16*)(p + (size_t)2 * 1024 * 1024);
  _Float16* Vpk = (_Float16*)(p + (size_t)4 * 1024 * 1024);
  _Float16* Opk = (_Float16*)(p + (size_t)6 * 1024 * 1024);
  _Float16* wts = (_Float16*)(p + (size_t)14 * 1024 * 1024);
  float* lsump = (float*)(p + (size_t)14 * 1024 * 1024 + 512 * 1024);
  float* maskf = lsump + 4 * 32768;

  qkv<<<dim3(128, 4), 512, 0, stream>>>(x1, x2, wq, bq, wk, bk, wv, bv, wm,
                                        wc1, wc2, kv_mask, Qpk, Kpk, Vpk, wts,
                                        maskf);
  attn<<<dim3(16, 16, 4), 256, 0, stream>>>(Qpk, Kpk, Vpk, maskf, Opk, lsump);
  post<<<dim3(128, 4), 512, 0, stream>>>(x1, Opk, lsump, wts, bm, bc1,
                                         bn_gamma, bn_beta, bn_mean, bn_var,
                                         bc2, out);
}